// Round 12
// baseline (59.778 us; speedup 1.0000x reference)
//
#include <hip/hip_runtime.h>

#define N 8192
#define D 128

typedef __attribute__((ext_vector_type(8))) short bf16x8;
typedef __attribute__((ext_vector_type(4))) float f32x4;
typedef unsigned int u32;
typedef unsigned short u16;

__device__ __forceinline__ u16 f2bf(float f) {
    u32 u = __float_as_uint(f);
    u += 0x7FFF + ((u >> 16) & 1);   // round-to-nearest-even
    return (u16)(u >> 16);
}

// ---- kernel 1: streaming bf16 copy + row sqnorm + init ---------------------
__global__ __launch_bounds__(256) void k_prep(const float* __restrict__ x,
                                              u16* __restrict__ xbf,
                                              float* __restrict__ sq,
                                              u32* __restrict__ minkey,
                                              u32* __restrict__ ctr) {
    const int tid = threadIdx.x;
    const int r = blockIdx.x * 16 + (tid >> 4);
    const int lr = tid & 15;
    const float4* src = (const float4*)(x + (size_t)r * D + lr * 8);
    float4 v0 = src[0], v1 = src[1];
    union { u16 h[8]; uint4 v; } o;
    o.h[0] = f2bf(v0.x); o.h[1] = f2bf(v0.y); o.h[2] = f2bf(v0.z); o.h[3] = f2bf(v0.w);
    o.h[4] = f2bf(v1.x); o.h[5] = f2bf(v1.y); o.h[6] = f2bf(v1.z); o.h[7] = f2bf(v1.w);
    *(uint4*)(xbf + (size_t)r * D + lr * 8) = o.v;
    float s = v0.x * v0.x + v0.y * v0.y + v0.z * v0.z + v0.w * v0.w
            + v1.x * v1.x + v1.y * v1.y + v1.z * v1.z + v1.w * v1.w;
    s += __shfl_xor(s, 1); s += __shfl_xor(s, 2);
    s += __shfl_xor(s, 4); s += __shfl_xor(s, 8);
    if (lr == 0) { sq[r] = s; minkey[r] = 0xFFFFFFFFu; }
    if (blockIdx.x == 0 && tid < 128) ctr[tid] = 0;
}

// ---- kernel 2: LDS-free, barrier-free; A in regs, B ping-pong prefetch -----
// 2048 waves (8/CU, fully co-resident): wave = (64-row group rg) x (512-col
// sweep sw). Per chunk (64 cols): 16 MFMA/kk x 4. B-frags double-buffered in
// VGPRs; step s consumes bqb[s&1] then reloads it for step s+2 (-> ~2 MFMA
// steps of L2-latency cover; R5's depth-0 version had zero cover -> 77us).
// NO __threadfence (agent fence = L2 writeback+invalidate, R5-R9 +20us).
__global__ __launch_bounds__(256, 2) void k_neg(const u16* __restrict__ xbf,
                                                const float* __restrict__ sq,
                                                u32* __restrict__ minkey,
                                                u32* __restrict__ ap2,
                                                u32* __restrict__ ctr,
                                                float* __restrict__ out) {
    const int tid = threadIdx.x;
    const int lane = tid & 63;
    const int wid = blockIdx.x * 4 + (tid >> 6);
    const int rg = wid >> 4, sw = wid & 15;       // 128 row-groups x 16 sweeps
    const int row0 = rg * 64, cs = sw * 512;
    const int lr = lane & 15, lg = lane >> 4;
    const int tdiag = (sw == (rg >> 3)) ? (rg & 7) : -1;
    const float INF = __int_as_float(0x7F800000);

    // A fragments: this wave's 64 rows x 128 K (64 VGPR), loaded once, pinned
    bf16x8 af[4][4];
#pragma unroll
    for (int f = 0; f < 4; ++f)
#pragma unroll
        for (int kk = 0; kk < 4; ++kk)
            af[f][kk] = *(const bf16x8*)(xbf +
                (size_t)(row0 + f * 16 + lr) * D + kk * 32 + lg * 8);
#pragma unroll
    for (int f = 0; f < 4; ++f)
#pragma unroll
        for (int kk = 0; kk < 4; ++kk)
            asm volatile("" : "+v"(af[f][kk]));   // keep loads out of the loop

#define LOADB(buf, c0v, kkv)                                                   \
    _Pragma("unroll")                                                          \
    for (int fj = 0; fj < 4; ++fj)                                             \
        (buf)[fj] = *(const bf16x8*)(xbf +                                     \
            (size_t)((c0v) + fj * 16 + lr) * D + (kkv) * 32 + lg * 8);

    // prologue: prefetch steps 0 and 1
    bf16x8 bqb[2][4];
    LOADB(bqb[0], cs, 0)
    LOADB(bqb[1], cs, 1)

    float rmin[4][4] = {{INF, INF, INF, INF}, {INF, INF, INF, INF},
                        {INF, INF, INF, INF}, {INF, INF, INF, INF}};

#pragma unroll
    for (int t = 0; t < 8; ++t) {
        const int c0 = cs + t * 64;
        float sjv[4];
#pragma unroll
        for (int fj = 0; fj < 4; ++fj)
            sjv[fj] = sq[c0 + fj * 16 + lr];

        f32x4 acc[4][4] = {};
#pragma unroll
        for (int kk = 0; kk < 4; ++kk) {
            const int step = t * 4 + kk;          // compile-time constant
            // consume the buffer loaded 2 steps ago
#pragma unroll
            for (int fi = 0; fi < 4; ++fi)
#pragma unroll
                for (int fj = 0; fj < 4; ++fj)
                    acc[fi][fj] = __builtin_amdgcn_mfma_f32_16x16x32_bf16(
                        af[fi][kk], bqb[step & 1][fj], acc[fi][fj], 0, 0, 0);
            // re-issue this buffer for step+2
            if (step + 2 < 32) {
                const int t2 = (step + 2) >> 2, k2 = (step + 2) & 3;
                LOADB(bqb[step & 1], cs + t2 * 64, k2)
            }
        }

        if (t == tdiag) {
#pragma unroll
            for (int fi = 0; fi < 4; ++fi) {
                float rmx[4] = {-INF, -INF, -INF, -INF};
#pragma unroll
                for (int jj = 0; jj < 4; ++jj)
#pragma unroll
                    for (int fj = 0; fj < 4; ++fj) {
                        float v = fmaf(-2.f, acc[fi][fj][jj], sjv[fj]);
                        if (fj == fi) rmx[jj] = fmaxf(rmx[jj], v);
                        else rmin[fi][jj] = fminf(rmin[fi][jj], v);
                    }
#pragma unroll
                for (int jj = 0; jj < 4; ++jj) {
                    float v = rmx[jj];
                    v = fmaxf(v, __shfl_xor(v, 1));
                    v = fmaxf(v, __shfl_xor(v, 2));
                    v = fmaxf(v, __shfl_xor(v, 4));
                    v = fmaxf(v, __shfl_xor(v, 8));
                    if (lr == 0) {
                        const int gi = row0 + fi * 16 + lg * 4 + jj;
                        // device-scope atomic store: cross-XCD visible, no fence
                        atomicExch(&ap2[gi], __float_as_uint(fmaxf(sq[gi] + v, 0.f)));
                    }
                }
            }
        } else {
#pragma unroll
            for (int fi = 0; fi < 4; ++fi)
#pragma unroll
                for (int jj = 0; jj < 4; ++jj)
#pragma unroll
                    for (int fj = 0; fj < 4; ++fj)
                        rmin[fi][jj] = fminf(rmin[fi][jj],
                                             fmaf(-2.f, acc[fi][fj][jj], sjv[fj]));
        }
    }
#undef LOADB

    // per-wave reduce + one atomicMin per row
#pragma unroll
    for (int fi = 0; fi < 4; ++fi)
#pragma unroll
        for (int jj = 0; jj < 4; ++jj) {
            float v = rmin[fi][jj];
            v = fminf(v, __shfl_xor(v, 1));
            v = fminf(v, __shfl_xor(v, 2));
            v = fminf(v, __shfl_xor(v, 4));
            v = fminf(v, __shfl_xor(v, 8));
            if (lr == 0) {
                const int gi = row0 + fi * 16 + lg * 4 + jj;
                atomicMin(&minkey[gi], __float_as_uint(fmaxf(sq[gi] + v, 0.f)));
            }
        }

    // drain this wave's atomics (wave-local, NOT a cache fence), then signal
    asm volatile("s_waitcnt vmcnt(0)" ::: "memory");
    u32 old = 0;
    if (lane == 0) old = atomicAdd(&ctr[rg], 1u);
    old = __shfl(old, 0);
    if (old == 15u) {   // last of the 16 sweep-waves for this row-group
        const int gi = row0 + lane;
        u32 mk = atomicAdd(&minkey[gi], 0u);   // device-scope atomic read
        u32 ab = atomicOr(&ap2[gi], 0u);       // device-scope atomic read
        out[gi] = fmaxf(sqrtf(__uint_as_float(ab)) - sqrtf(__uint_as_float(mk)) + 1.f,
                        0.f);
    }
}

extern "C" void kernel_launch(void* const* d_in, const int* in_sizes, int n_in,
                              void* d_out, int out_size, void* d_ws, size_t ws_size,
                              hipStream_t stream) {
    const float* x = (const float*)d_in[0];
    float* out = (float*)d_out;

    char* ws = (char*)d_ws;
    u16* xbf = (u16*)ws;                                // 2 MB bf16 copy
    float* sq = (float*)(ws + 2097152);                 // 32 KB
    u32* minkey = (u32*)(ws + 2097152 + 32768);         // 32 KB
    u32* ap2 = (u32*)(ws + 2097152 + 65536);            // 32 KB
    u32* ctr = (u32*)(ws + 2097152 + 98304);            // 512 B

    k_prep<<<N / 16, 256, 0, stream>>>(x, xbf, sq, minkey, ctr);
    k_neg<<<512, 256, 0, stream>>>(xbf, sq, minkey, ap2, ctr, out);
}